// Round 6
// baseline (969.682 us; speedup 1.0000x reference)
//
#include <hip/hip_runtime.h>

// Problem constants
#define HH 22
#define WW 22
#define HWN 484
#define NBATCH 64
#define SDIM 8
#define NMAPS (NBATCH*HWN)      // 30976
#define PW 24                   // padded row stride
#define CELLS 576               // 24x24 padded tile
#define PADW 24
#define PADSZ (PADW*PADW)
#define INVC (1.f/14992384.f)   // 1/(NMAPS*HWN)

// 9-tap neighborhood from a contiguous padded tile (stride-1 lane access = conflict-free)
#define LD9(A, idx) \
  float x0=(A)[(idx)-PW-1], x1=(A)[(idx)-PW], x2=(A)[(idx)-PW+1], \
        x3=(A)[(idx)-1],    x4=(A)[(idx)],    x5=(A)[(idx)+1], \
        x6=(A)[(idx)+PW-1], x7=(A)[(idx)+PW], x8=(A)[(idx)+PW+1]
#define DOT9W(w9, init) \
  fmaf((w9)[0],x0,fmaf((w9)[1],x1,fmaf((w9)[2],x2,fmaf((w9)[3],x3,fmaf((w9)[4],x4, \
  fmaf((w9)[5],x5,fmaf((w9)[6],x6,fmaf((w9)[7],x7,fmaf((w9)[8],x8,(init))))))))))

#define LOAD_NB(arr, bb) do { \
    nb[0]=(arr)[(bb)-PADW-1]; nb[1]=(arr)[(bb)-PADW]; nb[2]=(arr)[(bb)-PADW+1]; \
    nb[3]=(arr)[(bb)-1];      nb[4]=(arr)[(bb)];      nb[5]=(arr)[(bb)+1]; \
    nb[6]=(arr)[(bb)+PADW-1]; nb[7]=(arr)[(bb)+PADW]; nb[8]=(arr)[(bb)+PADW+1]; } while(0)

// -------------------------------------------------- conv(1->8) stats pass
__global__ __launch_bounds__(576) void k_stats(const float* __restrict__ src,
    const float* __restrict__ w, const float* __restrict__ b,
    float* __restrict__ Sg, float* __restrict__ Qg)
{
    __shared__ float xin[2][CELLS];
    __shared__ float red[16];
    int tid=threadIdx.x;
    int i=tid/PW, j=tid-i*PW;
    bool inter = (i>=1 && i<=22 && j>=1 && j<=22);
    int p=(i-1)*22+(j-1);
    xin[0][tid]=0.f; xin[1][tid]=0.f;
    float accS[8], accQ[8];
#pragma unroll
    for(int c=0;c<8;++c){ accS[c]=0.f; accQ[c]=0.f; }
    int m0=blockIdx.x*16;
    if(inter) xin[0][tid]=src[(size_t)m0*HWN+p];
    __syncthreads();
    for(int mi=0;mi<16;++mi){
        int cur=mi&1;
        float nx=0.f;
        if(mi<15 && inter) nx=src[(size_t)(m0+mi+1)*HWN+p];
        if(inter){
            LD9(xin[cur], tid);
#pragma unroll
            for(int c=0;c<8;++c){
                float y=DOT9W(w+c*9, b[c]);
                accS[c]+=y; accQ[c]=fmaf(y,y,accQ[c]);
            }
        }
        if(mi<15 && inter) xin[cur^1][tid]=nx;
        __syncthreads();
    }
    if(tid<16) red[tid]=0.f;
    __syncthreads();
#pragma unroll
    for(int c=0;c<8;++c){
        float s=accS[c], q=accQ[c];
        for(int o=32;o;o>>=1){ s+=__shfl_down(s,o); q+=__shfl_down(q,o); }
        if((tid&63)==0){ atomicAdd(&red[c],s); atomicAdd(&red[8+c],q); }
    }
    __syncthreads();
    if(tid<8){ atomicAdd(&Sg[tid],red[tid]); atomicAdd(&Qg[tid],red[8+tid]); }
}

// ------ conv(1->8)+BN(in-block finalize)+ReLU+conv(8->1), out stats
__global__ __launch_bounds__(576) void k_convpair(const float* __restrict__ src, float* __restrict__ Ydst,
    const float* __restrict__ w1, const float* __restrict__ b1,
    const float* __restrict__ Sin, const float* __restrict__ Qin,
    const float* __restrict__ g, const float* __restrict__ be,
    const float* __restrict__ w2, const float* __restrict__ b2,
    float* __restrict__ Sg, float* __restrict__ Qg)
{
    __shared__ float xin[2][CELLS];
    __shared__ float z[8][CELLS];
    __shared__ float scs[8], shs[8];
    __shared__ float red[2];
    int tid=threadIdx.x;
    int i=tid/PW, j=tid-i*PW;
    bool inter = (i>=1 && i<=22 && j>=1 && j<=22);
    int p=(i-1)*22+(j-1);
    xin[0][tid]=0.f; xin[1][tid]=0.f;
#pragma unroll
    for(int c=0;c<8;++c) z[c][tid]=0.f;      // pad cells stay zero forever
    if(tid<8){
        float mean=Sin[tid]*INVC;
        float var=fmaf(-mean,mean,Qin[tid]*INVC);
        float sc=g[tid]*rsqrtf(var+1e-5f);
        scs[tid]=sc; shs[tid]=fmaf(-mean,sc,be[tid]);
    }
    float aS=0.f, aQ=0.f;
    float b2v=b2[0];
    int m0=blockIdx.x*16;
    if(inter) xin[0][tid]=src[(size_t)m0*HWN+p];
    __syncthreads();
    for(int mi=0;mi<16;++mi){
        int cur=mi&1;
        float nx=0.f;
        if(mi<15 && inter) nx=src[(size_t)(m0+mi+1)*HWN+p];
        if(inter){
            LD9(xin[cur], tid);
#pragma unroll
            for(int c=0;c<8;++c){
                float y=DOT9W(w1+c*9, b1[c]);
                y=fmaf(y,scs[c],shs[c]);
                z[c][tid]=y>0.f?y:0.f;
            }
        }
        if(mi<15 && inter) xin[cur^1][tid]=nx;
        __syncthreads();                 // z ready (stage for m+1 also done)
        if(inter){
            float y=b2v;
#pragma unroll
            for(int c=0;c<8;++c){
                LD9(z[c], tid);
                y=DOT9W(w2+c*9, y);
            }
            Ydst[(size_t)(m0+mi)*HWN+p]=y;
            aS+=y; aQ=fmaf(y,y,aQ);
        }
        __syncthreads();                 // protect z before next conv1
    }
    if(tid<2) red[tid]=0.f;
    __syncthreads();
    for(int o=32;o;o>>=1){ aS+=__shfl_down(aS,o); aQ+=__shfl_down(aQ,o); }
    if((tid&63)==0){ atomicAdd(&red[0],aS); atomicAdd(&red[1],aQ); }
    __syncthreads();
    if(tid==0){ atomicAdd(Sg,red[0]); atomicAdd(Qg,red[1]); }
}

// ---- BN affine + per-map softmax (in place on Y) fused with conv(1->8) stats
__global__ __launch_bounds__(576) void k_smax_stats(float* __restrict__ Y,
    const float* __restrict__ S2, const float* __restrict__ Q2,
    const float* __restrict__ g2, const float* __restrict__ be2,
    const float* __restrict__ w, const float* __restrict__ b,
    float* __restrict__ Sg, float* __restrict__ Qg)
{
    __shared__ float xin[CELLS];
    __shared__ float red9[9];
    __shared__ float red[16];
    int tid=threadIdx.x;
    int i=tid/PW, j=tid-i*PW;
    bool inter = (i>=1 && i<=22 && j>=1 && j<=22);
    int p=(i-1)*22+(j-1);
    float mean=S2[0]*INVC;
    float var=fmaf(-mean,mean,Q2[0]*INVC);
    float a=g2[0]*rsqrtf(var+1e-5f);
    float sh=fmaf(-mean,a,be2[0]);
    xin[tid]=0.f;
    float accS[8], accQ[8];
#pragma unroll
    for(int c=0;c<8;++c){ accS[c]=0.f; accQ[c]=0.f; }
    int m0=blockIdx.x*16;
    for(int mi=0;mi<16;++mi){
        size_t off=(size_t)(m0+mi)*HWN+p;
        // exp without max-shift: BN-normalized input, fp32-safe (validated R5)
        float e = inter ? __expf(fmaf(Y[off],a,sh)) : 0.f;
        float part=e;
        for(int o=32;o;o>>=1) part+=__shfl_down(part,o);
        if((tid&63)==0) red9[tid>>6]=part;
        xin[tid]=e;                       // pad lanes write 0
        __syncthreads();
        float sum=red9[0]+red9[1]+red9[2]+red9[3]+red9[4]+red9[5]+red9[6]+red9[7]+red9[8];
        float inv=1.f/sum;
        if(inter){
            Y[off]=e*inv;
            LD9(xin, tid);                // raw exp values; fold inv into dot
#pragma unroll
            for(int c=0;c<8;++c){
                float d=DOT9W(w+c*9, 0.f);
                float y=fmaf(inv,d,b[c]);
                accS[c]+=y; accQ[c]=fmaf(y,y,accQ[c]);
            }
        }
        __syncthreads();                  // protect xin & red9
    }
    if(tid<16) red[tid]=0.f;
    __syncthreads();
#pragma unroll
    for(int c=0;c<8;++c){
        float s=accS[c], q=accQ[c];
        for(int o=32;o;o>>=1){ s+=__shfl_down(s,o); q+=__shfl_down(q,o); }
        if((tid&63)==0){ atomicAdd(&red[c],s); atomicAdd(&red[8+c],q); }
    }
    __syncthreads();
    if(tid<8){ atomicAdd(&Sg[tid],red[tid]); atomicAdd(&Qg[tid],red[8+tid]); }
}

// -------- column softmax over p + conf + einsum, 4-way p-split
__global__ __launch_bounds__(512) void k_prop(const float* __restrict__ Y,
    const float* __restrict__ S4, const float* __restrict__ Q4,
    const float* __restrict__ g4, const float* __restrict__ be4,
    const float* __restrict__ state, float* __restrict__ prop, float* __restrict__ conf)
{
    int n=blockIdx.x;
    __shared__ float sst[8*HWN];
    __shared__ float part[4][121][10];
    int tid=threadIdx.x;
    for(int q=tid;q<8*HWN;q+=512) sst[q]=state[(size_t)n*8*HWN + q];
    __syncthreads();
    int tq=tid&127, pc=tid>>7;
    int t=blockIdx.y*121+tq;
    float mean=S4[0]*INVC;
    float var=fmaf(-mean,mean,Q4[0]*INVC);
    float a=g4[0]*rsqrtf(var+1e-5f);
    float sh=fmaf(-mean,a,be4[0]);
    if(tq<121){
        const float* col = Y + (size_t)n*HWN*HWN + t + (size_t)pc*121*HWN;
        const float* sp = sst + pc*121;
        float mx=-1e30f, ssum=0.f;
        float acc[8];
#pragma unroll
        for(int d=0;d<8;++d) acc[d]=0.f;
#pragma unroll 4
        for(int p=0;p<121;++p){
            float v=fmaf(col[(size_t)p*HWN], a, sh);
            float e=__expf(v);
            mx=fmaxf(mx,v); ssum+=e;
#pragma unroll
            for(int d=0;d<8;++d) acc[d]=fmaf(e, sp[d*HWN+p], acc[d]);
        }
        part[pc][tq][0]=ssum; part[pc][tq][1]=mx;
#pragma unroll
        for(int d=0;d<8;++d) part[pc][tq][2+d]=acc[d];
    }
    __syncthreads();
    if(pc==0 && tq<121){
        float ssum=part[0][tq][0]+part[1][tq][0]+part[2][tq][0]+part[3][tq][0];
        float mx=fmaxf(fmaxf(part[0][tq][1],part[1][tq][1]),fmaxf(part[2][tq][1],part[3][tq][1]));
        float inv=1.f/ssum;
        conf[(size_t)n*HWN+t]=__expf(mx)*inv;
#pragma unroll
        for(int d=0;d<8;++d){
            float acd=part[0][tq][2+d]+part[1][tq][2+d]+part[2][tq][2+d]+part[3][tq][2+d];
            prop[((size_t)n*8+d)*HWN+t]=acd*inv;
        }
    }
}

// ------------------------------------------------ response conv1: 10 -> 64
__global__ __launch_bounds__(256) void k_rp1(const float* __restrict__ prop,
    const float* __restrict__ dimp, const float* __restrict__ conf,
    const float* __restrict__ wf, const float* __restrict__ bfv, float* __restrict__ R1)
{
    int n=blockIdx.x, g=blockIdx.y;
    __shared__ float pin[10*PADSZ];
    int tid=threadIdx.x;
    for(int i=tid;i<10*PADSZ;i+=256) pin[i]=0.f;
    __syncthreads();
    for(int p=tid;p<HWN;p+=256){
        int i=p/WW, j=p-i*WW; int aa=(i+1)*PADW+j+1;
#pragma unroll
        for(int d=0;d<8;++d) pin[d*PADSZ+aa]=prop[((size_t)n*8+d)*HWN+p];
        pin[8*PADSZ+aa]=dimp[(size_t)n*HWN+p];
        pin[9*PADSZ+aa]=conf[(size_t)n*HWN+p];
    }
    __syncthreads();
    const float* wg = wf + (size_t)(g*16)*90;
    for(int p=tid;p<HWN;p+=256){
        int i=p/WW, j=p-i*WW; int aa=(i+1)*PADW+j+1;
        float acc[16];
#pragma unroll
        for(int o=0;o<16;++o) acc[o]=bfv[g*16+o];
#pragma unroll
        for(int c=0;c<10;++c){
            float nb[9]; int bb=c*PADSZ+aa;
            LOAD_NB(pin, bb);
#pragma unroll
            for(int o=0;o<16;++o){
                const float* w=wg+o*90+c*9;
#pragma unroll
                for(int t=0;t<9;++t) acc[o]=fmaf(w[t], nb[t], acc[o]);
            }
        }
#pragma unroll
        for(int o=0;o<16;++o){
            float y=acc[o];
            R1[((size_t)n*64 + g*16+o)*HWN+p]= y>0.f?y:0.f;
        }
    }
}

// ------------------------------------------------ response conv2: 64 -> 32
__global__ __launch_bounds__(512) void k_rp2(const float* __restrict__ R1,
    const float* __restrict__ wf, const float* __restrict__ bfv, float* __restrict__ R2)
{
    int n=blockIdx.x, g=blockIdx.y;
    __shared__ float xc[16*PADSZ];
    int tid=threadIdx.x;
    for(int i=tid;i<16*PADSZ;i+=512) xc[i]=0.f;
    int p=tid; bool act = p<HWN;
    int i=p/WW, j=p-i*WW, aa=(i+1)*PADW+j+1;
    float acc[8];
#pragma unroll
    for(int o=0;o<8;++o) acc[o]=0.f;
    for(int k=0;k<4;++k){
        __syncthreads();
        for(int q=tid;q<16*HWN;q+=512){
            int ic=q/HWN, pp=q-ic*HWN;
            int ii=pp/WW, jj=pp-ii*WW;
            xc[ic*PADSZ+(ii+1)*PADW+jj+1]=R1[((size_t)n*64 + k*16+ic)*HWN+pp];
        }
        __syncthreads();
        if(act){
#pragma unroll
            for(int ic=0;ic<16;++ic){
                float nb[9]; int bb=ic*PADSZ+aa;
                LOAD_NB(xc, bb);
#pragma unroll
                for(int o=0;o<8;++o){
                    const float* w = wf + ((size_t)(g*8+o)*64 + k*16+ic)*9;
#pragma unroll
                    for(int t=0;t<9;++t) acc[o]=fmaf(w[t], nb[t], acc[o]);
                }
            }
        }
    }
    if(act){
#pragma unroll
        for(int o=0;o<8;++o){
            float y=acc[o]+bfv[g*8+o];
            R2[((size_t)n*32+g*8+o)*HWN+p]= y>0.f?y:0.f;
        }
    }
}

// ------------------- response conv3: 32 -> 1, sigmoid, + per-n max pools
__global__ __launch_bounds__(512) void k_resp(const float* __restrict__ R2,
    const float* __restrict__ wf, const float* __restrict__ bfv,
    const float* __restrict__ dimp, float* __restrict__ fused,
    float* __restrict__ pool, float* __restrict__ out)
{
    int n=blockIdx.x;
    __shared__ float xc[16*PADSZ];
    __shared__ float redf[8], redd[8];
    int tid=threadIdx.x;
    for(int i=tid;i<16*PADSZ;i+=512) xc[i]=0.f;
    int p=tid; bool act=p<HWN;
    int i=p/WW, j=p-i*WW, aa=(i+1)*PADW+j+1;
    float acc=0.f;
    for(int k=0;k<2;++k){
        __syncthreads();
        for(int q=tid;q<16*HWN;q+=512){
            int ic=q/HWN, pp=q-ic*HWN;
            int ii=pp/WW, jj=pp-ii*WW;
            xc[ic*PADSZ+(ii+1)*PADW+jj+1]=R2[((size_t)n*32+k*16+ic)*HWN+pp];
        }
        __syncthreads();
        if(act){
#pragma unroll
            for(int ic=0;ic<16;++ic){
                float nb[9]; int bb=ic*PADSZ+aa;
                LOAD_NB(xc, bb);
                const float* w=wf+(size_t)(k*16+ic)*9;
#pragma unroll
                for(int t=0;t<9;++t) acc=fmaf(w[t], nb[t], acc);
            }
        }
    }
    float fval=-1e30f, dval=-1e30f;
    if(act){
        float y=acc+bfv[0];
        float s=1.f/(1.f+__expf(-y));
        fused[(size_t)n*HWN+p]=s;
        out[(size_t)n*9*HWN+p]=s;
        fval=s;
        dval=dimp[(size_t)n*HWN+p];
    }
    int lane=tid&63, wid=tid>>6;
    for(int o=32;o;o>>=1){ fval=fmaxf(fval,__shfl_xor(fval,o)); dval=fmaxf(dval,__shfl_xor(dval,o)); }
    if(lane==0){ redf[wid]=fval; redd[wid]=dval; }
    __syncthreads();
    if(tid==0){
        float fm=redf[0], dm=redd[0];
        for(int q=1;q<8;++q){ fm=fmaxf(fm,redf[q]); dm=fmaxf(dm,redd[q]); }
        pool[n*2+0]=dm; pool[n*2+1]=fm;
    }
}

// --------------------------------------------------------------- ConvGRU
__global__ __launch_bounds__(512) void k_gru(const float* __restrict__ dimp,
    const float* __restrict__ fused, const float* __restrict__ pool,
    const float* __restrict__ prop,
    const float* __restrict__ wr, const float* __restrict__ br,
    const float* __restrict__ wu, const float* __restrict__ bu,
    const float* __restrict__ wo, const float* __restrict__ bo,
    float* __restrict__ out)
{
    int n=blockIdx.x;
    __shared__ float sg[12*PADSZ];
    __shared__ float pr[8*PADSZ];
    int tid=threadIdx.x;
    for(int i=tid;i<12*PADSZ;i+=512) sg[i]=0.f;
    for(int i=tid;i<8*PADSZ;i+=512) pr[i]=0.f;
    __syncthreads();
    float p0=pool[n*2+0], p1=pool[n*2+1];
    for(int p=tid;p<HWN;p+=512){
        int i=p/WW, j=p-i*WW, aa=(i+1)*PADW+j+1;
        sg[0*PADSZ+aa]=dimp[(size_t)n*HWN+p];
        sg[1*PADSZ+aa]=fused[(size_t)n*HWN+p];
        sg[2*PADSZ+aa]=p0;
        sg[3*PADSZ+aa]=p1;
#pragma unroll
        for(int d=0;d<8;++d) sg[(4+d)*PADSZ+aa]=prop[((size_t)n*8+d)*HWN+p];
    }
    __syncthreads();
    int p=tid; bool act=p<HWN;
    int i=p/WW, j=p-i*WW, aa=(i+1)*PADW+j+1;
    float upd[8];
    if(act){
        float ua[8], ra[8];
#pragma unroll
        for(int o=0;o<8;++o){ ua[o]=bu[o]; ra[o]=br[o]; }
#pragma unroll
        for(int ic=0;ic<12;++ic){
            float nb[9]; int bb=ic*PADSZ+aa;
            LOAD_NB(sg, bb);
#pragma unroll
            for(int o=0;o<8;++o){
                const float* wup=wu+((size_t)o*12+ic)*9;
                const float* wrp=wr+((size_t)o*12+ic)*9;
#pragma unroll
                for(int t=0;t<9;++t){
                    ua[o]=fmaf(wup[t], nb[t], ua[o]);
                    ra[o]=fmaf(wrp[t], nb[t], ra[o]);
                }
            }
        }
#pragma unroll
        for(int o=0;o<8;++o){
            upd[o]=1.f/(1.f+__expf(-ua[o]));
            float rst=1.f/(1.f+__expf(-ra[o]));
            pr[o*PADSZ+aa]=sg[(4+o)*PADSZ+aa]*rst;
        }
    }
    __syncthreads();
    if(act){
        float oa[8];
#pragma unroll
        for(int o=0;o<8;++o) oa[o]=bo[o];
#pragma unroll
        for(int ic=0;ic<12;++ic){
            const float* srcp = (ic<4)? (sg+ic*PADSZ) : (pr+(ic-4)*PADSZ);
            float nb[9]; int bb=aa;
            LOAD_NB(srcp, bb);
#pragma unroll
            for(int o=0;o<8;++o){
                const float* wop=wo+((size_t)o*12+ic)*9;
#pragma unroll
                for(int t=0;t<9;++t) oa[o]=fmaf(wop[t], nb[t], oa[o]);
            }
        }
#pragma unroll
        for(int o=0;o<8;++o){
            float od=tanhf(oa[o]);
            float ph=sg[(4+o)*PADSZ+aa];
            float sn=ph*(1.f-upd[o])+od*upd[o];
            out[((size_t)n*9+1+o)*HWN+p]=sn;
        }
    }
}

// ===========================================================================
extern "C" void kernel_launch(void* const* d_in, const int* in_sizes, int n_in,
                              void* d_out, int out_size, void* d_ws, size_t ws_size,
                              hipStream_t stream)
{
    (void)in_sizes; (void)n_in; (void)out_size; (void)ws_size;
    float* ws=(float*)d_ws;
    float* Y     = ws;                       // 14,992,384 floats
    float* PROP  = ws + 14992384;            // 247,808
    float* CONF  = PROP + 247808;            // 30,976
    float* FUSED = CONF + 30976;             // 30,976
    float* POOL  = FUSED + 30976;            // 128
    float* STATS = POOL + 128;               // 36
    float* R1    = ws;                       // alias Y (dead after k_prop)
    float* R2    = ws + 4000000;

    const float* cv    = (const float*)d_in[0];
    const float* state = (const float*)d_in[1];
    const float* dimp  = (const float*)d_in[2];
    float* out = (float*)d_out;

    hipMemsetAsync(STATS, 0, 36*sizeof(float), stream);

    float *S1=STATS,*Q1=STATS+8,*S2=STATS+16,*Q2=STATS+17,*S3=STATS+18,*Q3=STATS+26,*S4=STATS+34,*Q4=STATS+35;

    const float* cv1_w1=(const float*)d_in[3];  const float* cv1_b1=(const float*)d_in[4];
    const float* cv1_g1=(const float*)d_in[5];  const float* cv1_be1=(const float*)d_in[6];
    const float* cv1_w2=(const float*)d_in[7];  const float* cv1_b2=(const float*)d_in[8];
    const float* cv1_g2=(const float*)d_in[9];  const float* cv1_be2=(const float*)d_in[10];
    const float* cv2_w1=(const float*)d_in[11]; const float* cv2_b1=(const float*)d_in[12];
    const float* cv2_g1=(const float*)d_in[13]; const float* cv2_be1=(const float*)d_in[14];
    const float* cv2_w2=(const float*)d_in[15]; const float* cv2_b2=(const float*)d_in[16];
    const float* cv2_g2=(const float*)d_in[17]; const float* cv2_be2=(const float*)d_in[18];
    const float* rp1_w=(const float*)d_in[19];  const float* rp1_b=(const float*)d_in[20];
    const float* rp2_w=(const float*)d_in[21];  const float* rp2_b=(const float*)d_in[22];
    const float* resp_w=(const float*)d_in[23]; const float* resp_b=(const float*)d_in[24];
    const float* gru_rw=(const float*)d_in[25]; const float* gru_rb=(const float*)d_in[26];
    const float* gru_uw=(const float*)d_in[27]; const float* gru_ub=(const float*)d_in[28];
    const float* gru_ow=(const float*)d_in[29]; const float* gru_ob=(const float*)d_in[30];

    // cv1 stack
    k_stats<<<1936,576,0,stream>>>(cv, cv1_w1, cv1_b1, S1, Q1);
    k_convpair<<<1936,576,0,stream>>>(cv, Y, cv1_w1, cv1_b1, S1, Q1, cv1_g1, cv1_be1,
                                      cv1_w2, cv1_b2, S2, Q2);
    // BN2 affine + per-map softmax + cv2 conv1 stats (fused)
    k_smax_stats<<<1936,576,0,stream>>>(Y, S2, Q2, cv1_g2, cv1_be2, cv2_w1, cv2_b1, S3, Q3);
    // cv2 stack (in place on Y)
    k_convpair<<<1936,576,0,stream>>>(Y, Y, cv2_w1, cv2_b1, S3, Q3, cv2_g1, cv2_be1,
                                      cv2_w2, cv2_b2, S4, Q4);
    // column softmax over p + conf + propagation einsum (4-way p-split)
    k_prop<<<dim3(64,4),512,0,stream>>>(Y, S4, Q4, cv2_g2, cv2_be2, state, PROP, CONF);
    // response head
    k_rp1<<<dim3(64,4),256,0,stream>>>(PROP, dimp, CONF, rp1_w, rp1_b, R1);
    k_rp2<<<dim3(64,4),512,0,stream>>>(R1, rp2_w, rp2_b, R2);
    k_resp<<<64,512,0,stream>>>(R2, resp_w, resp_b, dimp, FUSED, POOL, out);
    // ConvGRU
    k_gru<<<64,512,0,stream>>>(dimp, FUSED, POOL, PROP,
                               gru_rw, gru_rb, gru_uw, gru_ub, gru_ow, gru_ob, out);
}

// Round 7
// 902.552 us; speedup vs baseline: 1.0744x; 1.0744x over previous
//
#include <hip/hip_runtime.h>

// Problem constants
#define HH 22
#define WW 22
#define HWN 484
#define NBATCH 64
#define SDIM 8
#define NMAPS (NBATCH*HWN)      // 30976
#define PADW 24                 // tail kernels' padded stride
#define PADSZ 576
#define INVC (1.f/14992384.f)   // 1/(NMAPS*HWN)

// ---- wave-per-map conv geometry: 25-wide skewed padded tile ----
#define CPW 25
#define XSZ 600                 // per-wave tile floats (max cell 599)

__device__ __forceinline__ int cellof(int r,int c){   // r,c in [-1,22]
    int rr=r+1, cc=c+1;
    return rr*CPW + cc + ((rr>>1)&1);                 // parity skew -> odd/even banks alternate by row-pair
}

struct Geo {
    int stc[8];                 // staging cells for lane's 8 flat pixels
    int tbA[4], tbB[4];         // 4 tap-row bases per patch (read +0..+3)
    int zA0,zA1,zB0,zB1;        // z/output cells (2 rows x 2 cols per patch)
    int rA0,rB0;                // flat map offsets of patch top-left
    bool hasB;
};

__device__ __forceinline__ void mkgeo(int lane, Geo& G){
    G.hasB = (lane < 57);       // patch B = lane+64 valid while <=120
#pragma unroll
    for(int k=0;k<4;++k){ int p=lane*4+k; int r=p/22; G.stc[k]=cellof(r,p-r*22); }
#pragma unroll
    for(int k=0;k<4;++k){
        int p=(lane+64)*4+k; int r=p/22;
        G.stc[4+k]= G.hasB ? cellof(r,p-r*22) : 0;
    }
    int prA=lane/11, pcA=lane-prA*11;
    int pB = G.hasB ? lane+64 : 0;
    int prB=pB/11, pcB=pB-prB*11;
#pragma unroll
    for(int kr=0;kr<4;++kr){
        G.tbA[kr]=cellof(2*prA-1+kr, 2*pcA-1);
        G.tbB[kr]=cellof(2*prB-1+kr, 2*pcB-1);
    }
    G.zA0=cellof(2*prA,2*pcA);   G.zA1=cellof(2*prA+1,2*pcA);
    G.zB0=cellof(2*prB,2*pcB);   G.zB1=cellof(2*prB+1,2*pcB);
    G.rA0=2*prA*22+2*pcA;        G.rB0=2*prB*22+2*pcB;
}

__device__ __forceinline__ void ldtaps(const float* xs, const int tb[4], float T[4][4]){
#pragma unroll
    for(int kr=0;kr<4;++kr)
#pragma unroll
        for(int kc=0;kc<4;++kc) T[kr][kc]=xs[tb[kr]+kc];
}

// 2x2 patch conv from 4x4 register taps
__device__ __forceinline__ void conv1p(const float T[4][4], const float* __restrict__ w9, float init,
                                       float&y00,float&y01,float&y10,float&y11){
    y00=init;y01=init;y10=init;y11=init;
#pragma unroll
    for(int kr=0;kr<3;++kr)
#pragma unroll
        for(int kc=0;kc<3;++kc){
            float wv=w9[kr*3+kc];
            y00=fmaf(wv,T[kr][kc],y00);     y01=fmaf(wv,T[kr][kc+1],y01);
            y10=fmaf(wv,T[kr+1][kc],y10);   y11=fmaf(wv,T[kr+1][kc+1],y11);
        }
}
__device__ __forceinline__ void conv2p(const float T[4][4], const float* __restrict__ w9,
                                       float&y00,float&y01,float&y10,float&y11){
#pragma unroll
    for(int kr=0;kr<3;++kr)
#pragma unroll
        for(int kc=0;kc<3;++kc){
            float wv=w9[kr*3+kc];
            y00=fmaf(wv,T[kr][kc],y00);     y01=fmaf(wv,T[kr][kc+1],y01);
            y10=fmaf(wv,T[kr+1][kc],y10);   y11=fmaf(wv,T[kr+1][kc+1],y11);
        }
}

#define LOAD_NB(arr, bb) do { \
    nb[0]=(arr)[(bb)-PADW-1]; nb[1]=(arr)[(bb)-PADW]; nb[2]=(arr)[(bb)-PADW+1]; \
    nb[3]=(arr)[(bb)-1];      nb[4]=(arr)[(bb)];      nb[5]=(arr)[(bb)+1]; \
    nb[6]=(arr)[(bb)+PADW-1]; nb[7]=(arr)[(bb)+PADW]; nb[8]=(arr)[(bb)+PADW+1]; } while(0)

// -------------------------------------------------- conv(1->8) stats pass
__global__ __launch_bounds__(256) void k_stats(const float* __restrict__ src,
    const float* __restrict__ w, const float* __restrict__ b,
    float* __restrict__ Sg, float* __restrict__ Qg)
{
    __shared__ float xsall[4*XSZ];
    __shared__ float redS[8], redQ[8];
    int tid=threadIdx.x, lane=tid&63, wv=tid>>6;
    float* xs=xsall+wv*XSZ;
    for(int q=tid;q<4*XSZ;q+=256) xsall[q]=0.f;
    if(tid<8){ redS[tid]=0.f; redQ[tid]=0.f; }
    __syncthreads();
    Geo G; mkgeo(lane,G);
    float accS[8], accQ[8];
#pragma unroll
    for(int c=0;c<8;++c){ accS[c]=0.f; accQ[c]=0.f; }
    int W=blockIdx.x*4+wv;
    for(int mi=0;mi<4;++mi){
        const float4* s4=(const float4*)(src+(size_t)(W*4+mi)*HWN);
        float4 va=s4[lane];
        float4 vb= G.hasB ? s4[lane+64] : make_float4(0.f,0.f,0.f,0.f);
        xs[G.stc[0]]=va.x; xs[G.stc[1]]=va.y; xs[G.stc[2]]=va.z; xs[G.stc[3]]=va.w;
        if(G.hasB){ xs[G.stc[4]]=vb.x; xs[G.stc[5]]=vb.y; xs[G.stc[6]]=vb.z; xs[G.stc[7]]=vb.w; }
        float tA[4][4], tB[4][4];
        ldtaps(xs,G.tbA,tA); ldtaps(xs,G.tbB,tB);
#pragma unroll
        for(int c=0;c<8;++c){
            const float* w9=w+c*9; float bc=b[c];
            float a00,a01,a10,a11,q00,q01,q10,q11;
            conv1p(tA,w9,bc,a00,a01,a10,a11);
            conv1p(tB,w9,bc,q00,q01,q10,q11);
            float s=a00+a01+a10+a11;
            float q=fmaf(a00,a00,fmaf(a01,a01,fmaf(a10,a10,a11*a11)));
            if(G.hasB){
                s+=q00+q01+q10+q11;
                q+=fmaf(q00,q00,fmaf(q01,q01,fmaf(q10,q10,q11*q11)));
            }
            accS[c]+=s; accQ[c]+=q;
        }
    }
#pragma unroll
    for(int c=0;c<8;++c){
        float s=accS[c], q=accQ[c];
        for(int o=32;o;o>>=1){ s+=__shfl_down(s,o); q+=__shfl_down(q,o); }
        if(lane==0){ atomicAdd(&redS[c],s); atomicAdd(&redQ[c],q); }
    }
    __syncthreads();
    if(tid<8){ atomicAdd(&Sg[tid],redS[tid]); atomicAdd(&Qg[tid],redQ[tid]); }
}

// ------ conv(1->8)+BN(in-wave finalize)+ReLU+conv(8->1), out stats; wave-per-map
__global__ __launch_bounds__(256) void k_convpair(const float* __restrict__ src, float* __restrict__ Ydst,
    const float* __restrict__ w1, const float* __restrict__ b1,
    const float* __restrict__ Sin, const float* __restrict__ Qin,
    const float* __restrict__ g, const float* __restrict__ be,
    const float* __restrict__ w2, const float* __restrict__ b2,
    float* __restrict__ Sg, float* __restrict__ Qg)
{
    __shared__ float xsall[4*XSZ];
    __shared__ float zsall[4*XSZ];
    __shared__ float redS[2];
    int tid=threadIdx.x, lane=tid&63, wv=tid>>6;
    float* xs=xsall+wv*XSZ;
    float* zs=zsall+wv*XSZ;
    for(int q=tid;q<4*XSZ;q+=256){ xsall[q]=0.f; zsall[q]=0.f; }
    if(tid<2) redS[tid]=0.f;
    __syncthreads();
    Geo G; mkgeo(lane,G);
    float scv[8], shv[8];
#pragma unroll
    for(int c=0;c<8;++c){
        float mean=Sin[c]*INVC;
        float var=fmaf(-mean,mean,Qin[c]*INVC);
        float sc=g[c]*rsqrtf(var+1e-5f);
        scv[c]=sc; shv[c]=fmaf(-mean,sc,be[c]);
    }
    float b2v=b2[0];
    float aS=0.f, aQ=0.f;
    int W=blockIdx.x*4+wv;
    for(int mi=0;mi<4;++mi){
        size_t mbase=(size_t)(W*4+mi)*HWN;
        const float4* s4=(const float4*)(src+mbase);
        float4 va=s4[lane];
        float4 vb= G.hasB ? s4[lane+64] : make_float4(0.f,0.f,0.f,0.f);
        xs[G.stc[0]]=va.x; xs[G.stc[1]]=va.y; xs[G.stc[2]]=va.z; xs[G.stc[3]]=va.w;
        if(G.hasB){ xs[G.stc[4]]=vb.x; xs[G.stc[5]]=vb.y; xs[G.stc[6]]=vb.z; xs[G.stc[7]]=vb.w; }
        float tA[4][4], tB[4][4];
        ldtaps(xs,G.tbA,tA); ldtaps(xs,G.tbB,tB);
        float oA00=b2v,oA01=b2v,oA10=b2v,oA11=b2v;
        float oB00=b2v,oB01=b2v,oB10=b2v,oB11=b2v;
#pragma unroll
        for(int c=0;c<8;++c){
            const float* w9=w1+c*9; float bc=b1[c];
            float a00,a01,a10,a11,q00,q01,q10,q11;
            conv1p(tA,w9,bc,a00,a01,a10,a11);
            conv1p(tB,w9,bc,q00,q01,q10,q11);
            float sc=scv[c], sh=shv[c];
            a00=fmaf(a00,sc,sh); a01=fmaf(a01,sc,sh); a10=fmaf(a10,sc,sh); a11=fmaf(a11,sc,sh);
            a00=a00>0.f?a00:0.f; a01=a01>0.f?a01:0.f; a10=a10>0.f?a10:0.f; a11=a11>0.f?a11:0.f;
            zs[G.zA0]=a00; zs[G.zA0+1]=a01; zs[G.zA1]=a10; zs[G.zA1+1]=a11;
            if(G.hasB){
                q00=fmaf(q00,sc,sh); q01=fmaf(q01,sc,sh); q10=fmaf(q10,sc,sh); q11=fmaf(q11,sc,sh);
                q00=q00>0.f?q00:0.f; q01=q01>0.f?q01:0.f; q10=q10>0.f?q10:0.f; q11=q11>0.f?q11:0.f;
                zs[G.zB0]=q00; zs[G.zB0+1]=q01; zs[G.zB1]=q10; zs[G.zB1+1]=q11;
            }
            // intra-wave LDS in-order: reads below see all lanes' writes above
            float zA[4][4], zB[4][4];
            ldtaps(zs,G.tbA,zA); ldtaps(zs,G.tbB,zB);
            const float* v9=w2+c*9;
            conv2p(zA,v9,oA00,oA01,oA10,oA11);
            conv2p(zB,v9,oB00,oB01,oB10,oB11);
        }
        float* yp=Ydst+mbase;
        yp[G.rA0]=oA00; yp[G.rA0+1]=oA01; yp[G.rA0+22]=oA10; yp[G.rA0+23]=oA11;
        aS+=oA00+oA01+oA10+oA11;
        aQ=fmaf(oA00,oA00,fmaf(oA01,oA01,fmaf(oA10,oA10,fmaf(oA11,oA11,aQ))));
        if(G.hasB){
            yp[G.rB0]=oB00; yp[G.rB0+1]=oB01; yp[G.rB0+22]=oB10; yp[G.rB0+23]=oB11;
            aS+=oB00+oB01+oB10+oB11;
            aQ=fmaf(oB00,oB00,fmaf(oB01,oB01,fmaf(oB10,oB10,fmaf(oB11,oB11,aQ))));
        }
    }
    for(int o=32;o;o>>=1){ aS+=__shfl_down(aS,o); aQ+=__shfl_down(aQ,o); }
    if(lane==0){ atomicAdd(&redS[0],aS); atomicAdd(&redS[1],aQ); }
    __syncthreads();
    if(tid==0) atomicAdd(Sg,redS[0]);
    if(tid==1) atomicAdd(Qg,redS[1]);
}

// ---- BN affine + per-map softmax (in place on Y) + conv(1->8) stats; wave-per-map
__global__ __launch_bounds__(256) void k_smax_stats(float* __restrict__ Y,
    const float* __restrict__ S2, const float* __restrict__ Q2,
    const float* __restrict__ g2, const float* __restrict__ be2,
    const float* __restrict__ w, const float* __restrict__ b,
    float* __restrict__ Sg, float* __restrict__ Qg)
{
    __shared__ float xsall[4*XSZ];
    __shared__ float redS[8], redQ[8];
    int tid=threadIdx.x, lane=tid&63, wv=tid>>6;
    float* xs=xsall+wv*XSZ;
    for(int q=tid;q<4*XSZ;q+=256) xsall[q]=0.f;
    if(tid<8){ redS[tid]=0.f; redQ[tid]=0.f; }
    __syncthreads();
    Geo G; mkgeo(lane,G);
    float mean=S2[0]*INVC;
    float var=fmaf(-mean,mean,Q2[0]*INVC);
    float a=g2[0]*rsqrtf(var+1e-5f);
    float sh=fmaf(-mean,a,be2[0]);
    float accS[8], accQ[8];
#pragma unroll
    for(int c=0;c<8;++c){ accS[c]=0.f; accQ[c]=0.f; }
    int W=blockIdx.x*4+wv;
    for(int mi=0;mi<4;++mi){
        size_t mbase=(size_t)(W*4+mi)*HWN;
        float4* y4=(float4*)(Y+mbase);
        float4 va=y4[lane];
        // exp without max-shift: BN-normalized input, fp32-safe (validated R5/R6)
        float e0=__expf(fmaf(va.x,a,sh)), e1=__expf(fmaf(va.y,a,sh));
        float e2=__expf(fmaf(va.z,a,sh)), e3=__expf(fmaf(va.w,a,sh));
        float e4=0.f,e5=0.f,e6=0.f,e7=0.f;
        if(G.hasB){
            float4 vb=y4[lane+64];
            e4=__expf(fmaf(vb.x,a,sh)); e5=__expf(fmaf(vb.y,a,sh));
            e6=__expf(fmaf(vb.z,a,sh)); e7=__expf(fmaf(vb.w,a,sh));
        }
        xs[G.stc[0]]=e0; xs[G.stc[1]]=e1; xs[G.stc[2]]=e2; xs[G.stc[3]]=e3;
        if(G.hasB){ xs[G.stc[4]]=e4; xs[G.stc[5]]=e5; xs[G.stc[6]]=e6; xs[G.stc[7]]=e7; }
        float ms=(e0+e1)+(e2+e3)+((e4+e5)+(e6+e7));
        for(int o=32;o;o>>=1) ms+=__shfl_xor(ms,o);
        float inv=1.f/ms;
        y4[lane]=make_float4(e0*inv,e1*inv,e2*inv,e3*inv);
        if(G.hasB) y4[lane+64]=make_float4(e4*inv,e5*inv,e6*inv,e7*inv);
        float tA[4][4], tB[4][4];
        ldtaps(xs,G.tbA,tA); ldtaps(xs,G.tbB,tB);
#pragma unroll
        for(int c=0;c<8;++c){
            const float* w9=w+c*9; float bc=b[c];
            float a00,a01,a10,a11,q00,q01,q10,q11;
            conv1p(tA,w9,0.f,a00,a01,a10,a11);
            conv1p(tB,w9,0.f,q00,q01,q10,q11);
            a00=fmaf(inv,a00,bc); a01=fmaf(inv,a01,bc); a10=fmaf(inv,a10,bc); a11=fmaf(inv,a11,bc);
            float s=a00+a01+a10+a11;
            float q=fmaf(a00,a00,fmaf(a01,a01,fmaf(a10,a10,a11*a11)));
            if(G.hasB){
                q00=fmaf(inv,q00,bc); q01=fmaf(inv,q01,bc); q10=fmaf(inv,q10,bc); q11=fmaf(inv,q11,bc);
                s+=q00+q01+q10+q11;
                q+=fmaf(q00,q00,fmaf(q01,q01,fmaf(q10,q10,q11*q11)));
            }
            accS[c]+=s; accQ[c]+=q;
        }
    }
#pragma unroll
    for(int c=0;c<8;++c){
        float s=accS[c], q=accQ[c];
        for(int o=32;o;o>>=1){ s+=__shfl_down(s,o); q+=__shfl_down(q,o); }
        if(lane==0){ atomicAdd(&redS[c],s); atomicAdd(&redQ[c],q); }
    }
    __syncthreads();
    if(tid<8){ atomicAdd(&Sg[tid],redS[tid]); atomicAdd(&Qg[tid],redQ[tid]); }
}

// -------- column softmax over p + conf + einsum, 4-way p-split
__global__ __launch_bounds__(512) void k_prop(const float* __restrict__ Y,
    const float* __restrict__ S4, const float* __restrict__ Q4,
    const float* __restrict__ g4, const float* __restrict__ be4,
    const float* __restrict__ state, float* __restrict__ prop, float* __restrict__ conf)
{
    int n=blockIdx.x;
    __shared__ float sst[8*HWN];
    __shared__ float part[4][121][10];
    int tid=threadIdx.x;
    for(int q=tid;q<8*HWN;q+=512) sst[q]=state[(size_t)n*8*HWN + q];
    __syncthreads();
    int tq=tid&127, pc=tid>>7;
    int t=blockIdx.y*121+tq;
    float mean=S4[0]*INVC;
    float var=fmaf(-mean,mean,Q4[0]*INVC);
    float a=g4[0]*rsqrtf(var+1e-5f);
    float sh=fmaf(-mean,a,be4[0]);
    if(tq<121){
        const float* col = Y + (size_t)n*HWN*HWN + t + (size_t)pc*121*HWN;
        const float* sp = sst + pc*121;
        float mx=-1e30f, ssum=0.f;
        float acc[8];
#pragma unroll
        for(int d=0;d<8;++d) acc[d]=0.f;
#pragma unroll 4
        for(int p=0;p<121;++p){
            float v=fmaf(col[(size_t)p*HWN], a, sh);
            float e=__expf(v);
            mx=fmaxf(mx,v); ssum+=e;
#pragma unroll
            for(int d=0;d<8;++d) acc[d]=fmaf(e, sp[d*HWN+p], acc[d]);
        }
        part[pc][tq][0]=ssum; part[pc][tq][1]=mx;
#pragma unroll
        for(int d=0;d<8;++d) part[pc][tq][2+d]=acc[d];
    }
    __syncthreads();
    if(pc==0 && tq<121){
        float ssum=part[0][tq][0]+part[1][tq][0]+part[2][tq][0]+part[3][tq][0];
        float mx=fmaxf(fmaxf(part[0][tq][1],part[1][tq][1]),fmaxf(part[2][tq][1],part[3][tq][1]));
        float inv=1.f/ssum;
        conf[(size_t)n*HWN+t]=__expf(mx)*inv;
#pragma unroll
        for(int d=0;d<8;++d){
            float acd=part[0][tq][2+d]+part[1][tq][2+d]+part[2][tq][2+d]+part[3][tq][2+d];
            prop[((size_t)n*8+d)*HWN+t]=acd*inv;
        }
    }
}

// ------------------------------------------------ response conv1: 10 -> 64
__global__ __launch_bounds__(256) void k_rp1(const float* __restrict__ prop,
    const float* __restrict__ dimp, const float* __restrict__ conf,
    const float* __restrict__ wf, const float* __restrict__ bfv, float* __restrict__ R1)
{
    int n=blockIdx.x, g=blockIdx.y;
    __shared__ float pin[10*PADSZ];
    int tid=threadIdx.x;
    for(int i=tid;i<10*PADSZ;i+=256) pin[i]=0.f;
    __syncthreads();
    for(int p=tid;p<HWN;p+=256){
        int i=p/WW, j=p-i*WW; int aa=(i+1)*PADW+j+1;
#pragma unroll
        for(int d=0;d<8;++d) pin[d*PADSZ+aa]=prop[((size_t)n*8+d)*HWN+p];
        pin[8*PADSZ+aa]=dimp[(size_t)n*HWN+p];
        pin[9*PADSZ+aa]=conf[(size_t)n*HWN+p];
    }
    __syncthreads();
    const float* wg = wf + (size_t)(g*16)*90;
    for(int p=tid;p<HWN;p+=256){
        int i=p/WW, j=p-i*WW; int aa=(i+1)*PADW+j+1;
        float acc[16];
#pragma unroll
        for(int o=0;o<16;++o) acc[o]=bfv[g*16+o];
#pragma unroll
        for(int c=0;c<10;++c){
            float nb[9]; int bb=c*PADSZ+aa;
            LOAD_NB(pin, bb);
#pragma unroll
            for(int o=0;o<16;++o){
                const float* w=wg+o*90+c*9;
#pragma unroll
                for(int t=0;t<9;++t) acc[o]=fmaf(w[t], nb[t], acc[o]);
            }
        }
#pragma unroll
        for(int o=0;o<16;++o){
            float y=acc[o];
            R1[((size_t)n*64 + g*16+o)*HWN+p]= y>0.f?y:0.f;
        }
    }
}

// ------------------------------------------------ response conv2: 64 -> 32
__global__ __launch_bounds__(512) void k_rp2(const float* __restrict__ R1,
    const float* __restrict__ wf, const float* __restrict__ bfv, float* __restrict__ R2)
{
    int n=blockIdx.x, g=blockIdx.y;
    __shared__ float xc[16*PADSZ];
    int tid=threadIdx.x;
    for(int i=tid;i<16*PADSZ;i+=512) xc[i]=0.f;
    int p=tid; bool act = p<HWN;
    int i=p/WW, j=p-i*WW, aa=(i+1)*PADW+j+1;
    float acc[8];
#pragma unroll
    for(int o=0;o<8;++o) acc[o]=0.f;
    for(int k=0;k<4;++k){
        __syncthreads();
        for(int q=tid;q<16*HWN;q+=512){
            int ic=q/HWN, pp=q-ic*HWN;
            int ii=pp/WW, jj=pp-ii*WW;
            xc[ic*PADSZ+(ii+1)*PADW+jj+1]=R1[((size_t)n*64 + k*16+ic)*HWN+pp];
        }
        __syncthreads();
        if(act){
#pragma unroll
            for(int ic=0;ic<16;++ic){
                float nb[9]; int bb=ic*PADSZ+aa;
                LOAD_NB(xc, bb);
#pragma unroll
                for(int o=0;o<8;++o){
                    const float* w = wf + ((size_t)(g*8+o)*64 + k*16+ic)*9;
#pragma unroll
                    for(int t=0;t<9;++t) acc[o]=fmaf(w[t], nb[t], acc[o]);
                }
            }
        }
    }
    if(act){
#pragma unroll
        for(int o=0;o<8;++o){
            float y=acc[o]+bfv[g*8+o];
            R2[((size_t)n*32+g*8+o)*HWN+p]= y>0.f?y:0.f;
        }
    }
}

// ------------------- response conv3: 32 -> 1, sigmoid, + per-n max pools
__global__ __launch_bounds__(512) void k_resp(const float* __restrict__ R2,
    const float* __restrict__ wf, const float* __restrict__ bfv,
    const float* __restrict__ dimp, float* __restrict__ fused,
    float* __restrict__ pool, float* __restrict__ out)
{
    int n=blockIdx.x;
    __shared__ float xc[16*PADSZ];
    __shared__ float redf[8], redd[8];
    int tid=threadIdx.x;
    for(int i=tid;i<16*PADSZ;i+=512) xc[i]=0.f;
    int p=tid; bool act=p<HWN;
    int i=p/WW, j=p-i*WW, aa=(i+1)*PADW+j+1;
    float acc=0.f;
    for(int k=0;k<2;++k){
        __syncthreads();
        for(int q=tid;q<16*HWN;q+=512){
            int ic=q/HWN, pp=q-ic*HWN;
            int ii=pp/WW, jj=pp-ii*WW;
            xc[ic*PADSZ+(ii+1)*PADW+jj+1]=R2[((size_t)n*32+k*16+ic)*HWN+pp];
        }
        __syncthreads();
        if(act){
#pragma unroll
            for(int ic=0;ic<16;++ic){
                float nb[9]; int bb=ic*PADSZ+aa;
                LOAD_NB(xc, bb);
                const float* w=wf+(size_t)(k*16+ic)*9;
#pragma unroll
                for(int t=0;t<9;++t) acc=fmaf(w[t], nb[t], acc);
            }
        }
    }
    float fval=-1e30f, dval=-1e30f;
    if(act){
        float y=acc+bfv[0];
        float s=1.f/(1.f+__expf(-y));
        fused[(size_t)n*HWN+p]=s;
        out[(size_t)n*9*HWN+p]=s;
        fval=s;
        dval=dimp[(size_t)n*HWN+p];
    }
    int lane=tid&63, wid=tid>>6;
    for(int o=32;o;o>>=1){ fval=fmaxf(fval,__shfl_xor(fval,o)); dval=fmaxf(dval,__shfl_xor(dval,o)); }
    if(lane==0){ redf[wid]=fval; redd[wid]=dval; }
    __syncthreads();
    if(tid==0){
        float fm=redf[0], dm=redd[0];
        for(int q=1;q<8;++q){ fm=fmaxf(fm,redf[q]); dm=fmaxf(dm,redd[q]); }
        pool[n*2+0]=dm; pool[n*2+1]=fm;
    }
}

// --------------------------------------------------------------- ConvGRU
__global__ __launch_bounds__(512) void k_gru(const float* __restrict__ dimp,
    const float* __restrict__ fused, const float* __restrict__ pool,
    const float* __restrict__ prop,
    const float* __restrict__ wr, const float* __restrict__ br,
    const float* __restrict__ wu, const float* __restrict__ bu,
    const float* __restrict__ wo, const float* __restrict__ bo,
    float* __restrict__ out)
{
    int n=blockIdx.x;
    __shared__ float sg[12*PADSZ];
    __shared__ float pr[8*PADSZ];
    int tid=threadIdx.x;
    for(int i=tid;i<12*PADSZ;i+=512) sg[i]=0.f;
    for(int i=tid;i<8*PADSZ;i+=512) pr[i]=0.f;
    __syncthreads();
    float p0=pool[n*2+0], p1=pool[n*2+1];
    for(int p=tid;p<HWN;p+=512){
        int i=p/WW, j=p-i*WW, aa=(i+1)*PADW+j+1;
        sg[0*PADSZ+aa]=dimp[(size_t)n*HWN+p];
        sg[1*PADSZ+aa]=fused[(size_t)n*HWN+p];
        sg[2*PADSZ+aa]=p0;
        sg[3*PADSZ+aa]=p1;
#pragma unroll
        for(int d=0;d<8;++d) sg[(4+d)*PADSZ+aa]=prop[((size_t)n*8+d)*HWN+p];
    }
    __syncthreads();
    int p=tid; bool act=p<HWN;
    int i=p/WW, j=p-i*WW, aa=(i+1)*PADW+j+1;
    float upd[8];
    if(act){
        float ua[8], ra[8];
#pragma unroll
        for(int o=0;o<8;++o){ ua[o]=bu[o]; ra[o]=br[o]; }
#pragma unroll
        for(int ic=0;ic<12;++ic){
            float nb[9]; int bb=ic*PADSZ+aa;
            LOAD_NB(sg, bb);
#pragma unroll
            for(int o=0;o<8;++o){
                const float* wup=wu+((size_t)o*12+ic)*9;
                const float* wrp=wr+((size_t)o*12+ic)*9;
#pragma unroll
                for(int t=0;t<9;++t){
                    ua[o]=fmaf(wup[t], nb[t], ua[o]);
                    ra[o]=fmaf(wrp[t], nb[t], ra[o]);
                }
            }
        }
#pragma unroll
        for(int o=0;o<8;++o){
            upd[o]=1.f/(1.f+__expf(-ua[o]));
            float rst=1.f/(1.f+__expf(-ra[o]));
            pr[o*PADSZ+aa]=sg[(4+o)*PADSZ+aa]*rst;
        }
    }
    __syncthreads();
    if(act){
        float oa[8];
#pragma unroll
        for(int o=0;o<8;++o) oa[o]=bo[o];
#pragma unroll
        for(int ic=0;ic<12;++ic){
            const float* srcp = (ic<4)? (sg+ic*PADSZ) : (pr+(ic-4)*PADSZ);
            float nb[9]; int bb=aa;
            LOAD_NB(srcp, bb);
#pragma unroll
            for(int o=0;o<8;++o){
                const float* wop=wo+((size_t)o*12+ic)*9;
#pragma unroll
                for(int t=0;t<9;++t) oa[o]=fmaf(wop[t], nb[t], oa[o]);
            }
        }
#pragma unroll
        for(int o=0;o<8;++o){
            float od=tanhf(oa[o]);
            float ph=sg[(4+o)*PADSZ+aa];
            float sn=ph*(1.f-upd[o])+od*upd[o];
            out[((size_t)n*9+1+o)*HWN+p]=sn;
        }
    }
}

// ===========================================================================
extern "C" void kernel_launch(void* const* d_in, const int* in_sizes, int n_in,
                              void* d_out, int out_size, void* d_ws, size_t ws_size,
                              hipStream_t stream)
{
    (void)in_sizes; (void)n_in; (void)out_size; (void)ws_size;
    float* ws=(float*)d_ws;
    float* Y     = ws;                       // 14,992,384 floats
    float* PROP  = ws + 14992384;            // 247,808
    float* CONF  = PROP + 247808;            // 30,976
    float* FUSED = CONF + 30976;             // 30,976
    float* POOL  = FUSED + 30976;            // 128
    float* STATS = POOL + 128;               // 36
    float* R1    = ws;                       // alias Y (dead after k_prop)
    float* R2    = ws + 4000000;

    const float* cv    = (const float*)d_in[0];
    const float* state = (const float*)d_in[1];
    const float* dimp  = (const float*)d_in[2];
    float* out = (float*)d_out;

    hipMemsetAsync(STATS, 0, 36*sizeof(float), stream);

    float *S1=STATS,*Q1=STATS+8,*S2=STATS+16,*Q2=STATS+17,*S3=STATS+18,*Q3=STATS+26,*S4=STATS+34,*Q4=STATS+35;

    const float* cv1_w1=(const float*)d_in[3];  const float* cv1_b1=(const float*)d_in[4];
    const float* cv1_g1=(const float*)d_in[5];  const float* cv1_be1=(const float*)d_in[6];
    const float* cv1_w2=(const float*)d_in[7];  const float* cv1_b2=(const float*)d_in[8];
    const float* cv1_g2=(const float*)d_in[9];  const float* cv1_be2=(const float*)d_in[10];
    const float* cv2_w1=(const float*)d_in[11]; const float* cv2_b1=(const float*)d_in[12];
    const float* cv2_g1=(const float*)d_in[13]; const float* cv2_be1=(const float*)d_in[14];
    const float* cv2_w2=(const float*)d_in[15]; const float* cv2_b2=(const float*)d_in[16];
    const float* cv2_g2=(const float*)d_in[17]; const float* cv2_be2=(const float*)d_in[18];
    const float* rp1_w=(const float*)d_in[19];  const float* rp1_b=(const float*)d_in[20];
    const float* rp2_w=(const float*)d_in[21];  const float* rp2_b=(const float*)d_in[22];
    const float* resp_w=(const float*)d_in[23]; const float* resp_b=(const float*)d_in[24];
    const float* gru_rw=(const float*)d_in[25]; const float* gru_rb=(const float*)d_in[26];
    const float* gru_uw=(const float*)d_in[27]; const float* gru_ub=(const float*)d_in[28];
    const float* gru_ow=(const float*)d_in[29]; const float* gru_ob=(const float*)d_in[30];

    // cv1 stack (wave-per-map kernels: 1936 blocks x 4 waves x 4-map chain)
    k_stats<<<1936,256,0,stream>>>(cv, cv1_w1, cv1_b1, S1, Q1);
    k_convpair<<<1936,256,0,stream>>>(cv, Y, cv1_w1, cv1_b1, S1, Q1, cv1_g1, cv1_be1,
                                      cv1_w2, cv1_b2, S2, Q2);
    // BN2 affine + per-map softmax + cv2 conv1 stats (fused)
    k_smax_stats<<<1936,256,0,stream>>>(Y, S2, Q2, cv1_g2, cv1_be2, cv2_w1, cv2_b1, S3, Q3);
    // cv2 stack (in place on Y)
    k_convpair<<<1936,256,0,stream>>>(Y, Y, cv2_w1, cv2_b1, S3, Q3, cv2_g1, cv2_be1,
                                      cv2_w2, cv2_b2, S4, Q4);
    // column softmax over p + conf + propagation einsum (4-way p-split)
    k_prop<<<dim3(64,4),512,0,stream>>>(Y, S4, Q4, cv2_g2, cv2_be2, state, PROP, CONF);
    // response head
    k_rp1<<<dim3(64,4),256,0,stream>>>(PROP, dimp, CONF, rp1_w, rp1_b, R1);
    k_rp2<<<dim3(64,4),512,0,stream>>>(R1, rp2_w, rp2_b, R2);
    k_resp<<<64,512,0,stream>>>(R2, resp_w, resp_b, dimp, FUSED, POOL, out);
    // ConvGRU
    k_gru<<<64,512,0,stream>>>(dimp, FUSED, POOL, PROP,
                               gru_rw, gru_rb, gru_uw, gru_ub, gru_ow, gru_ob, out);
}